// Round 4
// baseline (632.694 us; speedup 1.0000x reference)
//
#include <hip/hip_runtime.h>
#include <cstddef>
#include <cstdint>

#define USER_COUNT_C 100000
#define ITEM_COUNT_C 100000
#define DIM_C 64
#define B_C 1024
#define NPOS_C 10
#define NTOP_C 50
#define CLAMP_C 40.0f
#define EPS_C 1e-5f

#define NGROUPS 6250          // 100000 / 16 item groups (exact)
#define GX 256                // item-group blocks (grid.x)
#define GY 4                  // user blocks: 4 x 256 users (grid.y)

using bf16x8 = __attribute__((ext_vector_type(8))) short;
using f32x4  = __attribute__((ext_vector_type(4))) float;

__global__ void zero_ws_kernel(float* __restrict__ ws) {
    ws[threadIdx.x] = 0.0f;  // B_C threads
}

// RNE fp32 -> bf16 bits
__device__ inline short f2bf(float x) {
    uint32_t b = __float_as_uint(x);
    uint32_t r = (b + 0x7fffu + ((b >> 16) & 1u)) >> 16;
    return (short)r;
}

__device__ inline bf16x8 cvt8(const float* __restrict__ p) {
    float4 v0 = *(const float4*)p;
    float4 v1 = *(const float4*)(p + 4);
    bf16x8 r;
    r[0] = f2bf(v0.x); r[1] = f2bf(v0.y); r[2] = f2bf(v0.z); r[3] = f2bf(v0.w);
    r[4] = f2bf(v1.x); r[5] = f2bf(v1.y); r[6] = f2bf(v1.z); r[7] = f2bf(v1.w);
    return r;
}

// item_bf16 frag-ready layout: group g (16 items), half h (k 0/1), quad q,
// item n16: 8 bf16 at ((g*2+h)*4+q)*128 + n16*8. Wave B-load = contiguous 1KB.
__global__ __launch_bounds__(256) void prep_items_kernel(
    const float* __restrict__ item_emb, short* __restrict__ item_bf16) {
    const int t = blockIdx.x * 256 + threadIdx.x;   // NGROUPS*128 total (exact)
    const int n16 = t & 15;
    const int q   = (t >> 4) & 3;
    const int h   = (t >> 6) & 1;
    const int g   = t >> 7;
    const int i   = g * 16 + n16;                   // always < ITEM_COUNT_C
    bf16x8 v = cvt8(item_emb + (size_t)i * DIM_C + h * 32 + q * 8);
    *(bf16x8*)(item_bf16 + (((size_t)g * 2 + h) * 4 + q) * 128 + n16 * 8) = v;
}

// exp_sum[b] = sum_i exp(clip(u_b . item_i, +-40)) * (1 - mask[b][i])
// Wave owns 64 users (4 A-frag pairs, resident); streams 16-item groups.
// All 18 VMEM per iter batch-issued before any wait -> high MLP. No LDS.
__global__ __launch_bounds__(256, 4) void expsum_mfma3_kernel(
    const float* __restrict__ user_emb,
    const short* __restrict__ item_bf16,
    const int*   __restrict__ batch_user,
    const float* __restrict__ mask,
    float*       __restrict__ exp_sum)
{
    const int tid  = threadIdx.x;
    const int wave = tid >> 6;
    const int lane = tid & 63;
    const int n16  = lane & 15;
    const int quad = lane >> 4;
    const int uBase = blockIdx.y * 256 + wave * 64;   // 64 users per wave

    // A fragments: 4 groups of 16 users, gathered + converted once
    bf16x8 a0[4], a1[4];
    #pragma unroll
    for (int j = 0; j < 4; ++j) {
        const int uidx = batch_user[uBase + j * 16 + n16];
        const float* us = user_emb + (size_t)uidx * DIM_C + quad * 8;
        a0[j] = cvt8(us);
        a1[j] = cvt8(us + 32);
    }

    // lane's mask row base: rows uBase+quad*4 + (j*16+reg), col g*16+n16
    const float* mrow = mask + (size_t)(uBase + quad * 4) * ITEM_COUNT_C;
    const short* ibase_p = item_bf16 + quad * 128 + n16 * 8;

    float accE[4][4];
    #pragma unroll
    for (int j = 0; j < 4; ++j)
        #pragma unroll
        for (int r = 0; r < 4; ++r) accE[j][r] = 0.f;

    for (int g = blockIdx.x; g < NGROUPS; g += GX) {
        // --- batched VMEM: 16 mask dwords + 2 x 1KB b-frags, all issued up front
        const uint32_t gcol = (uint32_t)g * 16u + (uint32_t)n16;
        float m[16];
        #pragma unroll
        for (int j = 0; j < 4; ++j)
            #pragma unroll
            for (int r = 0; r < 4; ++r)
                m[j * 4 + r] = mrow[(size_t)((uint32_t)(j * 16 + r) * 100000u + gcol)];

        const short* bp = ibase_p + (size_t)g * 1024;
        const bf16x8 b0 = *(const bf16x8*)bp;
        const bf16x8 b1 = *(const bf16x8*)(bp + 512);

        // --- MFMA: 64 users x 16 items x K=64
        f32x4 acc[4];
        #pragma unroll
        for (int j = 0; j < 4; ++j) {
            acc[j] = (f32x4){0.f, 0.f, 0.f, 0.f};
            acc[j] = __builtin_amdgcn_mfma_f32_16x16x32_bf16(a0[j], b0, acc[j], 0, 0, 0);
            acc[j] = __builtin_amdgcn_mfma_f32_16x16x32_bf16(a1[j], b1, acc[j], 0, 0, 0);
        }

        // --- epilogue: clamp -> exp -> (1-mask) -> accumulate
        #pragma unroll
        for (int j = 0; j < 4; ++j)
            #pragma unroll
            for (int r = 0; r < 4; ++r) {
                const float sc = fminf(fmaxf(acc[j][r], -CLAMP_C), CLAMP_C);
                accE[j][r] += __expf(sc) * (1.0f - m[j * 4 + r]);
            }
    }

    // reduce across the 16 item-lanes (lane bits 0..3), same quad
    #pragma unroll
    for (int off = 1; off < 16; off <<= 1)
        #pragma unroll
        for (int j = 0; j < 4; ++j)
            #pragma unroll
            for (int r = 0; r < 4; ++r)
                accE[j][r] += __shfl_xor(accE[j][r], off, 64);

    if (n16 == 0) {
        #pragma unroll
        for (int j = 0; j < 4; ++j)
            #pragma unroll
            for (int r = 0; r < 4; ++r)
                atomicAdd(&exp_sum[uBase + j * 16 + quad * 4 + r], accE[j][r]);
    }
}

// Fallback (ws too small for bf16 item buffer): fp32 items from global
__global__ __launch_bounds__(256) void expsum_fallback_kernel(
    const float* __restrict__ user_emb,
    const float* __restrict__ item_emb,
    const int*   __restrict__ batch_user,
    const float* __restrict__ mask,
    float*       __restrict__ exp_sum)
{
    const int tid  = threadIdx.x;
    const int wave = tid >> 6;
    const int lane = tid & 63;
    const int n16  = lane & 15;
    const int quad = lane >> 4;
    const int rowBase = blockIdx.y * 64 + wave * 16;

    const int uidx = batch_user[rowBase + n16];
    const float* usrc = user_emb + (size_t)uidx * DIM_C + quad * 8;
    const bf16x8 a0 = cvt8(usrc);
    const bf16x8 a1 = cvt8(usrc + 32);

    float accExp[4] = {0.f, 0.f, 0.f, 0.f};

    for (int t = blockIdx.x; t < NGROUPS / 4; t += 64) {
        const int ibase = t * 64;
        bf16x8 b0[4], b1[4];
        #pragma unroll
        for (int s = 0; s < 4; ++s) {
            const int gi = ibase + s * 16 + n16;
            const float* isrc = item_emb + (size_t)gi * DIM_C + quad * 8;
            b0[s] = cvt8(isrc);
            b1[s] = cvt8(isrc + 32);
        }
        f32x4 acc[4];
        #pragma unroll
        for (int s = 0; s < 4; ++s) {
            acc[s] = (f32x4){0.f, 0.f, 0.f, 0.f};
            acc[s] = __builtin_amdgcn_mfma_f32_16x16x32_bf16(a0, b0[s], acc[s], 0, 0, 0);
            acc[s] = __builtin_amdgcn_mfma_f32_16x16x32_bf16(a1, b1[s], acc[s], 0, 0, 0);
        }
        #pragma unroll
        for (int s = 0; s < 4; ++s)
            #pragma unroll
            for (int reg = 0; reg < 4; ++reg) {
                const int row = rowBase + quad * 4 + reg;
                const float sc = fminf(fmaxf(acc[s][reg], -CLAMP_C), CLAMP_C);
                const float w = 1.0f - mask[(size_t)row * ITEM_COUNT_C + ibase + s * 16 + n16];
                accExp[reg] += __expf(sc) * w;
            }
    }
    #pragma unroll
    for (int off = 1; off < 16; off <<= 1)
        #pragma unroll
        for (int reg = 0; reg < 4; ++reg)
            accExp[reg] += __shfl_xor(accExp[reg], off, 64);
    if (n16 == 0)
        #pragma unroll
        for (int reg = 0; reg < 4; ++reg)
            atomicAdd(&exp_sum[rowBase + quad * 4 + reg], accExp[reg]);
}

// per-row: 60 sampled scores (exact fp32) + loss math -> row_loss[b]
__global__ void finalize_kernel(
    const float* __restrict__ user_emb,
    const float* __restrict__ item_emb,
    const int*   __restrict__ batch_user,
    const int*   __restrict__ pos_items,
    const int*   __restrict__ top_items,
    const float* __restrict__ exp_sum,
    const int*   __restrict__ is_final,
    float*       __restrict__ row_loss)
{
    __shared__ float ush[DIM_C];
    __shared__ float s_sh[NPOS_C + NTOP_C];
    const int b = blockIdx.x;
    const int tid = threadIdx.x;  // 64 threads
    const int uidx = batch_user[b];
    if (tid < 16)
        *(float4*)&ush[tid * 4] = *(const float4*)(user_emb + (size_t)uidx * DIM_C + tid * 4);
    __syncthreads();

    if (tid < NPOS_C + NTOP_C) {
        const int idx = (tid < NPOS_C) ? pos_items[b * NPOS_C + tid]
                                       : top_items[b * NTOP_C + (tid - NPOS_C)];
        const float* iv = item_emb + (size_t)idx * DIM_C;
        float s = 0.f;
        #pragma unroll
        for (int d4 = 0; d4 < 16; ++d4) {
            const float4 a = *(const float4*)(iv + d4 * 4);
            s += a.x * ush[d4 * 4 + 0] + a.y * ush[d4 * 4 + 1]
               + a.z * ush[d4 * 4 + 2] + a.w * ush[d4 * 4 + 3];
        }
        s_sh[tid] = fminf(fmaxf(s, -CLAMP_C), CLAMP_C);
    }
    __syncthreads();

    if (tid == 0) {
        const float E = exp_sum[b];
        float L;
        if (is_final[0] != 0) {
            float sumExpTop = 0.f, above_top = 0.f;
            for (int i = 0; i < NTOP_C / 2; ++i) {
                const float v = s_sh[NPOS_C + i];
                sumExpTop += __expf(v); above_top += v;
            }
            const float below2 = E - sumExpTop;
            float above_pos = 0.f;
            for (int i = 0; i < NPOS_C; ++i) above_pos += s_sh[i];
            float c = 0.f, below_pos = 0.f;
            for (int i = 0; i < NPOS_C; ++i) {
                c += __expf(s_sh[NPOS_C - 1 - i]);
                below_pos += __logf(fmaxf(c + below2, EPS_C));
            }
            float c2 = 0.f, below_top = 0.f;
            for (int i = 0; i < NTOP_C / 2; ++i) {
                c2 += __expf(s_sh[NPOS_C + NTOP_C / 2 - 1 - i]);
                below_top += __logf(fmaxf(c2 + below2, EPS_C));
            }
            const float pos_KD = below_pos - above_pos;
            float sumExpSub = 0.f, above_sub = 0.f;
            for (int i = 0; i < NTOP_C / 10; ++i) {
                const float v = s_sh[NPOS_C + i];
                sumExpSub += __expf(v); above_sub += v;
            }
            const float below2s = E - sumExpSub;
            float c3 = 0.f, below_sub = 0.f;
            for (int i = 0; i < NTOP_C / 10; ++i) {
                c3 += __expf(s_sh[NPOS_C + NTOP_C / 10 - 1 - i]);
                below_sub += __logf(fmaxf(c3 + below2s, EPS_C));
            }
            const float top_KD = (below_top - above_top) + (below_sub - above_sub);
            L = pos_KD + 0.5f * top_KD;
        } else {
            float sumExpTop = 0.f;
            for (int i = 0; i < NTOP_C; ++i) sumExpTop += __expf(s_sh[NPOS_C + i]);
            const float els = E - sumExpTop;
            L = 0.f;
            for (int j = 0; j < NPOS_C + NTOP_C; ++j) {
                const float a = s_sh[j];
                L += __logf(fmaxf(els + __expf(a), EPS_C)) - a;
            }
        }
        row_loss[b] = L;
    }
}

__global__ void reduce_kernel(const float* __restrict__ rl, float* __restrict__ out) {
    __shared__ float part[16];
    const int tid = threadIdx.x;  // 1024 threads = 16 waves
    float v = rl[tid];
    #pragma unroll
    for (int off = 32; off > 0; off >>= 1) v += __shfl_down(v, off, 64);
    if ((tid & 63) == 0) part[tid >> 6] = v;
    __syncthreads();
    if (tid == 0) {
        float s = 0.f;
        #pragma unroll
        for (int i = 0; i < 16; ++i) s += part[i];
        out[0] = s;
    }
}

extern "C" void kernel_launch(void* const* d_in, const int* in_sizes, int n_in,
                              void* d_out, int out_size, void* d_ws, size_t ws_size,
                              hipStream_t stream) {
    const float* user_emb   = (const float*)d_in[0];
    const float* item_emb   = (const float*)d_in[1];
    const int*   batch_user = (const int*)d_in[2];
    const int*   pos_items  = (const int*)d_in[3];
    const int*   top_items  = (const int*)d_in[4];
    const float* mask       = (const float*)d_in[5];
    const int*   is_final   = (const int*)d_in[6];
    float* out = (float*)d_out;

    float* exp_sum  = (float*)d_ws;       // [B_C]
    float* row_loss = exp_sum + B_C;      // [B_C]
    short* item_bf16 = (short*)(row_loss + B_C);
    const size_t need = 2 * B_C * sizeof(float)
                      + (size_t)NGROUPS * 1024 * sizeof(short);

    hipLaunchKernelGGL(zero_ws_kernel, dim3(1), dim3(B_C), 0, stream, exp_sum);
    if (ws_size >= need) {
        hipLaunchKernelGGL(prep_items_kernel, dim3(NGROUPS * 128 / 256), dim3(256),
                           0, stream, item_emb, item_bf16);
        hipLaunchKernelGGL(expsum_mfma3_kernel, dim3(GX, GY), dim3(256),
                           0, stream, user_emb, item_bf16, batch_user, mask, exp_sum);
    } else {
        hipLaunchKernelGGL(expsum_fallback_kernel, dim3(64, B_C / 64), dim3(256),
                           0, stream, user_emb, item_emb, batch_user, mask, exp_sum);
    }
    hipLaunchKernelGGL(finalize_kernel, dim3(B_C), dim3(64), 0, stream,
                       user_emb, item_emb, batch_user, pos_items, top_items,
                       exp_sum, is_final, row_loss);
    hipLaunchKernelGGL(reduce_kernel, dim3(1), dim3(B_C), 0, stream, row_loss, out);
}

// Round 5
// 604.329 us; speedup vs baseline: 1.0469x; 1.0469x over previous
//
#include <hip/hip_runtime.h>
#include <cstddef>
#include <cstdint>

#define USER_COUNT_C 100000
#define ITEM_COUNT_C 100000
#define DIM_C 64
#define B_C 1024
#define NPOS_C 10
#define NTOP_C 50
#define CLAMP_C 40.0f
#define EPS_C 1e-5f

#define NGROUPS 6250          // 100000/16 item groups (exact)
#define NCHUNKS 3125          // 100000/32 item chunks (exact)
#define GX 96                 // column-range blocks
#define GY 16                 // user blocks (64 users each)

using bf16x8 = __attribute__((ext_vector_type(8))) short;
using f32x4  = __attribute__((ext_vector_type(4))) float;

__global__ void zero_ws_kernel(float* __restrict__ ws) {
    ws[threadIdx.x] = 0.0f;  // B_C threads
}

// RNE fp32 -> bf16 bits
__device__ inline short f2bf(float x) {
    uint32_t b = __float_as_uint(x);
    uint32_t r = (b + 0x7fffu + ((b >> 16) & 1u)) >> 16;
    return (short)r;
}

__device__ inline bf16x8 cvt8(const float* __restrict__ p) {
    float4 v0 = *(const float4*)p;
    float4 v1 = *(const float4*)(p + 4);
    bf16x8 r;
    r[0] = f2bf(v0.x); r[1] = f2bf(v0.y); r[2] = f2bf(v0.z); r[3] = f2bf(v0.w);
    r[4] = f2bf(v1.x); r[5] = f2bf(v1.y); r[6] = f2bf(v1.z); r[7] = f2bf(v1.w);
    return r;
}

// item_bf16 frag-ready layout: group g (16 items), half h (k 0/1), quad q,
// item idx16: 8 bf16 at ((g*2+h)*4+q)*128 + idx16*8. Wave frag load = 1KB.
__global__ __launch_bounds__(256) void prep_items_kernel(
    const float* __restrict__ item_emb, short* __restrict__ item_bf16) {
    const int t = blockIdx.x * 256 + threadIdx.x;   // NGROUPS*128 total (exact)
    const int n16 = t & 15;
    const int q   = (t >> 4) & 3;
    const int h   = (t >> 6) & 1;
    const int g   = t >> 7;
    const int i   = g * 16 + n16;                   // always < ITEM_COUNT_C
    bf16x8 v = cvt8(item_emb + (size_t)i * DIM_C + h * 32 + q * 8);
    *(bf16x8*)(item_bf16 + (((size_t)g * 2 + h) * 4 + q) * 128 + n16 * 8) = v;
}

// exp_sum[b] = sum_i exp(clip(u_b . item_i, +-40)) * (1 - mask[b][i])
// ITEMS in A, USERS in B: C row=item(quad*4+reg), col=user(n16).
// Mask weights become per-lane float4 loads, sequential along each user row.
__global__ __launch_bounds__(256, 6) void expsum_mfma4_kernel(
    const float* __restrict__ user_emb,
    const short* __restrict__ item_bf16,
    const int*   __restrict__ batch_user,
    const float* __restrict__ mask,
    float*       __restrict__ exp_sum)
{
    const int tid  = threadIdx.x;
    const int wave = tid >> 6;
    const int lane = tid & 63;
    const int n16  = lane & 15;   // user index within wave's 16
    const int quad = lane >> 4;   // k-group / C row-group
    const int uBase = blockIdx.y * 64 + wave * 16;

    // B fragments (users), resident: k = quad*8+j (+32 for b1)
    const int uidx = batch_user[uBase + n16];
    const float* us = user_emb + (size_t)uidx * DIM_C + quad * 8;
    const bf16x8 b0 = cvt8(us);
    const bf16x8 b1 = cvt8(us + 32);

    // this lane's mask row (its user), columns streamed sequentially
    const float* mrow = mask + (size_t)(uBase + n16) * ITEM_COUNT_C;
    const short* fbase = item_bf16 + quad * 128 + n16 * 8;

    // contiguous chunk range of 32-item chunks
    const int c0 = (int)(((long)blockIdx.x * NCHUNKS) / GX);
    const int c1 = (int)(((long)(blockIdx.x + 1) * NCHUNKS) / GX);

    float accE = 0.f;

    auto body = [&](int c) {
        const short* fp = fbase + (size_t)c * 2048;           // 2 groups x 1024
        const bf16x8 a00 = *(const bf16x8*)fp;                // items 32c..+15, k lo
        const bf16x8 a01 = *(const bf16x8*)(fp + 512);        // k hi
        const bf16x8 a10 = *(const bf16x8*)(fp + 1024);       // items 32c+16..+31
        const bf16x8 a11 = *(const bf16x8*)(fp + 1536);
        const float4 m0 = *(const float4*)(mrow + c * 32 + quad * 4);
        const float4 m1 = *(const float4*)(mrow + c * 32 + 16 + quad * 4);

        f32x4 acc0 = (f32x4){0.f, 0.f, 0.f, 0.f};
        acc0 = __builtin_amdgcn_mfma_f32_16x16x32_bf16(a00, b0, acc0, 0, 0, 0);
        acc0 = __builtin_amdgcn_mfma_f32_16x16x32_bf16(a01, b1, acc0, 0, 0, 0);
        f32x4 acc1 = (f32x4){0.f, 0.f, 0.f, 0.f};
        acc1 = __builtin_amdgcn_mfma_f32_16x16x32_bf16(a10, b0, acc1, 0, 0, 0);
        acc1 = __builtin_amdgcn_mfma_f32_16x16x32_bf16(a11, b1, acc1, 0, 0, 0);

        const float* m0p = (const float*)&m0;
        const float* m1p = (const float*)&m1;
        #pragma unroll
        for (int r = 0; r < 4; ++r) {
            const float s0 = fminf(fmaxf(acc0[r], -CLAMP_C), CLAMP_C);
            accE += __expf(s0) * (1.0f - m0p[r]);
            const float s1 = fminf(fmaxf(acc1[r], -CLAMP_C), CLAMP_C);
            accE += __expf(s1) * (1.0f - m1p[r]);
        }
    };

    int c = c0;
    for (; c + 2 <= c1; c += 2) { body(c); body(c + 1); }
    if (c < c1) body(c);

    // reduce over quads (lane bits 4,5) -> per-user total
    accE += __shfl_xor(accE, 16, 64);
    accE += __shfl_xor(accE, 32, 64);
    if (quad == 0)
        atomicAdd(&exp_sum[uBase + n16], accE);
}

// Fallback (ws too small for bf16 item buffer): fp32 items from global
__global__ __launch_bounds__(256) void expsum_fallback_kernel(
    const float* __restrict__ user_emb,
    const float* __restrict__ item_emb,
    const int*   __restrict__ batch_user,
    const float* __restrict__ mask,
    float*       __restrict__ exp_sum)
{
    const int tid  = threadIdx.x;
    const int wave = tid >> 6;
    const int lane = tid & 63;
    const int n16  = lane & 15;
    const int quad = lane >> 4;
    const int rowBase = blockIdx.y * 64 + wave * 16;

    const int uidx = batch_user[rowBase + n16];
    const float* usrc = user_emb + (size_t)uidx * DIM_C + quad * 8;
    const bf16x8 a0 = cvt8(usrc);
    const bf16x8 a1 = cvt8(usrc + 32);

    float accExp[4] = {0.f, 0.f, 0.f, 0.f};

    for (int t = blockIdx.x; t < NGROUPS / 4; t += 64) {
        const int ibase = t * 64;
        bf16x8 b0[4], b1[4];
        #pragma unroll
        for (int s = 0; s < 4; ++s) {
            const int gi = ibase + s * 16 + n16;
            const float* isrc = item_emb + (size_t)gi * DIM_C + quad * 8;
            b0[s] = cvt8(isrc);
            b1[s] = cvt8(isrc + 32);
        }
        f32x4 acc[4];
        #pragma unroll
        for (int s = 0; s < 4; ++s) {
            acc[s] = (f32x4){0.f, 0.f, 0.f, 0.f};
            acc[s] = __builtin_amdgcn_mfma_f32_16x16x32_bf16(a0, b0[s], acc[s], 0, 0, 0);
            acc[s] = __builtin_amdgcn_mfma_f32_16x16x32_bf16(a1, b1[s], acc[s], 0, 0, 0);
        }
        #pragma unroll
        for (int s = 0; s < 4; ++s)
            #pragma unroll
            for (int reg = 0; reg < 4; ++reg) {
                const int row = rowBase + quad * 4 + reg;
                const float sc = fminf(fmaxf(acc[s][reg], -CLAMP_C), CLAMP_C);
                const float w = 1.0f - mask[(size_t)row * ITEM_COUNT_C + ibase + s * 16 + n16];
                accExp[reg] += __expf(sc) * w;
            }
    }
    #pragma unroll
    for (int off = 1; off < 16; off <<= 1)
        #pragma unroll
        for (int reg = 0; reg < 4; ++reg)
            accExp[reg] += __shfl_xor(accExp[reg], off, 64);
    if (n16 == 0)
        #pragma unroll
        for (int reg = 0; reg < 4; ++reg)
            atomicAdd(&exp_sum[rowBase + quad * 4 + reg], accExp[reg]);
}

// per-row: 60 sampled scores (exact fp32) + loss math -> row_loss[b]
__global__ void finalize_kernel(
    const float* __restrict__ user_emb,
    const float* __restrict__ item_emb,
    const int*   __restrict__ batch_user,
    const int*   __restrict__ pos_items,
    const int*   __restrict__ top_items,
    const float* __restrict__ exp_sum,
    const int*   __restrict__ is_final,
    float*       __restrict__ row_loss)
{
    __shared__ float ush[DIM_C];
    __shared__ float s_sh[NPOS_C + NTOP_C];
    const int b = blockIdx.x;
    const int tid = threadIdx.x;  // 64 threads
    const int uidx = batch_user[b];
    if (tid < 16)
        *(float4*)&ush[tid * 4] = *(const float4*)(user_emb + (size_t)uidx * DIM_C + tid * 4);
    __syncthreads();

    if (tid < NPOS_C + NTOP_C) {
        const int idx = (tid < NPOS_C) ? pos_items[b * NPOS_C + tid]
                                       : top_items[b * NTOP_C + (tid - NPOS_C)];
        const float* iv = item_emb + (size_t)idx * DIM_C;
        float s = 0.f;
        #pragma unroll
        for (int d4 = 0; d4 < 16; ++d4) {
            const float4 a = *(const float4*)(iv + d4 * 4);
            s += a.x * ush[d4 * 4 + 0] + a.y * ush[d4 * 4 + 1]
               + a.z * ush[d4 * 4 + 2] + a.w * ush[d4 * 4 + 3];
        }
        s_sh[tid] = fminf(fmaxf(s, -CLAMP_C), CLAMP_C);
    }
    __syncthreads();

    if (tid == 0) {
        const float E = exp_sum[b];
        float L;
        if (is_final[0] != 0) {
            float sumExpTop = 0.f, above_top = 0.f;
            for (int i = 0; i < NTOP_C / 2; ++i) {
                const float v = s_sh[NPOS_C + i];
                sumExpTop += __expf(v); above_top += v;
            }
            const float below2 = E - sumExpTop;
            float above_pos = 0.f;
            for (int i = 0; i < NPOS_C; ++i) above_pos += s_sh[i];
            float c = 0.f, below_pos = 0.f;
            for (int i = 0; i < NPOS_C; ++i) {
                c += __expf(s_sh[NPOS_C - 1 - i]);
                below_pos += __logf(fmaxf(c + below2, EPS_C));
            }
            float c2 = 0.f, below_top = 0.f;
            for (int i = 0; i < NTOP_C / 2; ++i) {
                c2 += __expf(s_sh[NPOS_C + NTOP_C / 2 - 1 - i]);
                below_top += __logf(fmaxf(c2 + below2, EPS_C));
            }
            const float pos_KD = below_pos - above_pos;
            float sumExpSub = 0.f, above_sub = 0.f;
            for (int i = 0; i < NTOP_C / 10; ++i) {
                const float v = s_sh[NPOS_C + i];
                sumExpSub += __expf(v); above_sub += v;
            }
            const float below2s = E - sumExpSub;
            float c3 = 0.f, below_sub = 0.f;
            for (int i = 0; i < NTOP_C / 10; ++i) {
                c3 += __expf(s_sh[NPOS_C + NTOP_C / 10 - 1 - i]);
                below_sub += __logf(fmaxf(c3 + below2s, EPS_C));
            }
            const float top_KD = (below_top - above_top) + (below_sub - above_sub);
            L = pos_KD + 0.5f * top_KD;
        } else {
            float sumExpTop = 0.f;
            for (int i = 0; i < NTOP_C; ++i) sumExpTop += __expf(s_sh[NPOS_C + i]);
            const float els = E - sumExpTop;
            L = 0.f;
            for (int j = 0; j < NPOS_C + NTOP_C; ++j) {
                const float a = s_sh[j];
                L += __logf(fmaxf(els + __expf(a), EPS_C)) - a;
            }
        }
        row_loss[b] = L;
    }
}

__global__ void reduce_kernel(const float* __restrict__ rl, float* __restrict__ out) {
    __shared__ float part[16];
    const int tid = threadIdx.x;  // 1024 threads = 16 waves
    float v = rl[tid];
    #pragma unroll
    for (int off = 32; off > 0; off >>= 1) v += __shfl_down(v, off, 64);
    if ((tid & 63) == 0) part[tid >> 6] = v;
    __syncthreads();
    if (tid == 0) {
        float s = 0.f;
        #pragma unroll
        for (int i = 0; i < 16; ++i) s += part[i];
        out[0] = s;
    }
}

extern "C" void kernel_launch(void* const* d_in, const int* in_sizes, int n_in,
                              void* d_out, int out_size, void* d_ws, size_t ws_size,
                              hipStream_t stream) {
    const float* user_emb   = (const float*)d_in[0];
    const float* item_emb   = (const float*)d_in[1];
    const int*   batch_user = (const int*)d_in[2];
    const int*   pos_items  = (const int*)d_in[3];
    const int*   top_items  = (const int*)d_in[4];
    const float* mask       = (const float*)d_in[5];
    const int*   is_final   = (const int*)d_in[6];
    float* out = (float*)d_out;

    float* exp_sum  = (float*)d_ws;       // [B_C]
    float* row_loss = exp_sum + B_C;      // [B_C]
    short* item_bf16 = (short*)(row_loss + B_C);
    const size_t need = 2 * B_C * sizeof(float)
                      + (size_t)NGROUPS * 1024 * sizeof(short);

    hipLaunchKernelGGL(zero_ws_kernel, dim3(1), dim3(B_C), 0, stream, exp_sum);
    if (ws_size >= need) {
        hipLaunchKernelGGL(prep_items_kernel, dim3(NGROUPS * 128 / 256), dim3(256),
                           0, stream, item_emb, item_bf16);
        hipLaunchKernelGGL(expsum_mfma4_kernel, dim3(GX, GY), dim3(256),
                           0, stream, user_emb, item_bf16, batch_user, mask, exp_sum);
    } else {
        hipLaunchKernelGGL(expsum_fallback_kernel, dim3(64, B_C / 64), dim3(256),
                           0, stream, user_emb, item_emb, batch_user, mask, exp_sum);
    }
    hipLaunchKernelGGL(finalize_kernel, dim3(B_C), dim3(64), 0, stream,
                       user_emb, item_emb, batch_user, pos_items, top_items,
                       exp_sum, is_final, row_loss);
    hipLaunchKernelGGL(reduce_kernel, dim3(1), dim3(B_C), 0, stream, row_loss, out);
}

// Round 6
// 593.176 us; speedup vs baseline: 1.0666x; 1.0188x over previous
//
#include <hip/hip_runtime.h>
#include <cstddef>
#include <cstdint>

#define USER_COUNT_C 100000
#define ITEM_COUNT_C 100000
#define DIM_C 64
#define B_C 1024
#define NPOS_C 10
#define NTOP_C 50
#define CLAMP_C 40.0f
#define EPS_C 1e-5f

#define NGROUPS 6250          // 100000/16 item groups (exact)
#define NCHUNKS 3125          // 100000/32 item chunks (exact)
#define GX 48                 // column-range blocks
#define GY 16                 // user blocks (64 users each); 768 blocks = 3/CU

using bf16x8 = __attribute__((ext_vector_type(8))) short;
using f32x4  = __attribute__((ext_vector_type(4))) float;

__global__ void zero_ws_kernel(float* __restrict__ ws) {
    ws[threadIdx.x] = 0.0f;  // B_C threads
}

// RNE fp32 -> bf16 bits
__device__ inline short f2bf(float x) {
    uint32_t b = __float_as_uint(x);
    uint32_t r = (b + 0x7fffu + ((b >> 16) & 1u)) >> 16;
    return (short)r;
}

__device__ inline bf16x8 cvt8(const float* __restrict__ p) {
    float4 v0 = *(const float4*)p;
    float4 v1 = *(const float4*)(p + 4);
    bf16x8 r;
    r[0] = f2bf(v0.x); r[1] = f2bf(v0.y); r[2] = f2bf(v0.z); r[3] = f2bf(v0.w);
    r[4] = f2bf(v1.x); r[5] = f2bf(v1.y); r[6] = f2bf(v1.z); r[7] = f2bf(v1.w);
    return r;
}

// item_bf16 frag-ready layout: group g (16 items), half h (k 0/1), quad q,
// item idx16: 8 bf16 at ((g*2+h)*4+q)*128 + idx16*8. Wave frag load = 1KB.
__global__ __launch_bounds__(256) void prep_items_kernel(
    const float* __restrict__ item_emb, short* __restrict__ item_bf16) {
    const int t = blockIdx.x * 256 + threadIdx.x;   // NGROUPS*128 total (exact)
    const int n16 = t & 15;
    const int q   = (t >> 4) & 3;
    const int h   = (t >> 6) & 1;
    const int g   = t >> 7;
    const int i   = g * 16 + n16;                   // always < ITEM_COUNT_C
    bf16x8 v = cvt8(item_emb + (size_t)i * DIM_C + h * 32 + q * 8);
    *(bf16x8*)(item_bf16 + (((size_t)g * 2 + h) * 4 + q) * 128 + n16 * 8) = v;
}

// exp_sum[b] = sum_i exp(clip(u_b . item_i, +-40)) * (1 - mask[b][i])
// ITEMS in A, USERS in B. Each WAVE owns 64 users (4 B-frag pairs resident);
// the block's chunk range is split across its 4 waves, so each 4KB item-frag
// chunk is loaded by exactly one wave (frag traffic 200MB total, was 800MB).
// Per iter: 12 batch-issued VMEM (8KB mask HBM + 4KB frag LLC), 16 MFMA.
__global__ __launch_bounds__(256, 3) void expsum_mfma5_kernel(
    const float* __restrict__ user_emb,
    const short* __restrict__ item_bf16,
    const int*   __restrict__ batch_user,
    const float* __restrict__ mask,
    float*       __restrict__ exp_sum)
{
    const int tid  = threadIdx.x;
    const int wave = tid >> 6;
    const int lane = tid & 63;
    const int n16  = lane & 15;   // user-in-group / item-in-group index
    const int quad = lane >> 4;   // k-group; C row-group (items)
    const int uBase = blockIdx.y * 64;     // block owns 64 users; wave owns all

    // B fragments: 4 user groups (j*16+n16), resident all kernel
    bf16x8 b0[4], b1[4];
    #pragma unroll
    for (int j = 0; j < 4; ++j) {
        const int uidx = batch_user[uBase + j * 16 + n16];
        const float* us = user_emb + (size_t)uidx * DIM_C + quad * 8;
        b0[j] = cvt8(us);
        b1[j] = cvt8(us + 32);
    }

    // lane's mask base: row = user (uBase + j*16 + n16), col = item
    const float* mbase = mask + (size_t)(uBase + n16) * ITEM_COUNT_C;
    const short* fbase = item_bf16 + quad * 128 + n16 * 8;

    const int c0 = (int)(((long)blockIdx.x * NCHUNKS) / GX);
    const int c1 = (int)(((long)(blockIdx.x + 1) * NCHUNKS) / GX);

    float accE[4] = {0.f, 0.f, 0.f, 0.f};

    for (int c = c0 + wave; c < c1; c += 4) {
        // --- batched VMEM: 8 mask float4 + 4 item frags
        float4 m[4][2];
        #pragma unroll
        for (int j = 0; j < 4; ++j)
            #pragma unroll
            for (int ig = 0; ig < 2; ++ig)
                m[j][ig] = *(const float4*)(mbase + (size_t)j * 16 * ITEM_COUNT_C
                                            + c * 32 + ig * 16 + quad * 4);

        const short* fp = fbase + (size_t)c * 2048;
        const bf16x8 a00 = *(const bf16x8*)fp;            // items 32c..+15, k lo
        const bf16x8 a01 = *(const bf16x8*)(fp + 512);    // k hi
        const bf16x8 a10 = *(const bf16x8*)(fp + 1024);   // items 32c+16..+31
        const bf16x8 a11 = *(const bf16x8*)(fp + 1536);

        // --- MFMA: 32 items x 64 users, K=64
        f32x4 acc[2][4];
        #pragma unroll
        for (int j = 0; j < 4; ++j) {
            acc[0][j] = (f32x4){0.f, 0.f, 0.f, 0.f};
            acc[0][j] = __builtin_amdgcn_mfma_f32_16x16x32_bf16(a00, b0[j], acc[0][j], 0, 0, 0);
            acc[0][j] = __builtin_amdgcn_mfma_f32_16x16x32_bf16(a01, b1[j], acc[0][j], 0, 0, 0);
            acc[1][j] = (f32x4){0.f, 0.f, 0.f, 0.f};
            acc[1][j] = __builtin_amdgcn_mfma_f32_16x16x32_bf16(a10, b0[j], acc[1][j], 0, 0, 0);
            acc[1][j] = __builtin_amdgcn_mfma_f32_16x16x32_bf16(a11, b1[j], acc[1][j], 0, 0, 0);
        }

        // --- epilogue: clamp -> exp -> (1-mask) -> accumulate per user group
        #pragma unroll
        for (int j = 0; j < 4; ++j)
            #pragma unroll
            for (int ig = 0; ig < 2; ++ig) {
                const float* mp = (const float*)&m[j][ig];
                #pragma unroll
                for (int r = 0; r < 4; ++r) {
                    const float sc = fminf(fmaxf(acc[ig][j][r], -CLAMP_C), CLAMP_C);
                    accE[j] += __expf(sc) * (1.0f - mp[r]);
                }
            }
    }

    // reduce over quads (lane bits 4,5): each user's partial lives in 4 lanes
    #pragma unroll
    for (int j = 0; j < 4; ++j) {
        accE[j] += __shfl_xor(accE[j], 16, 64);
        accE[j] += __shfl_xor(accE[j], 32, 64);
    }
    if (quad == 0) {
        #pragma unroll
        for (int j = 0; j < 4; ++j)
            atomicAdd(&exp_sum[uBase + j * 16 + n16], accE[j]);
    }
}

// Fallback (ws too small for bf16 item buffer): fp32 items from global
__global__ __launch_bounds__(256) void expsum_fallback_kernel(
    const float* __restrict__ user_emb,
    const float* __restrict__ item_emb,
    const int*   __restrict__ batch_user,
    const float* __restrict__ mask,
    float*       __restrict__ exp_sum)
{
    const int tid  = threadIdx.x;
    const int wave = tid >> 6;
    const int lane = tid & 63;
    const int n16  = lane & 15;
    const int quad = lane >> 4;
    const int rowBase = blockIdx.y * 64 + wave * 16;

    const int uidx = batch_user[rowBase + n16];
    const float* usrc = user_emb + (size_t)uidx * DIM_C + quad * 8;
    const bf16x8 a0 = cvt8(usrc);
    const bf16x8 a1 = cvt8(usrc + 32);

    float accExp[4] = {0.f, 0.f, 0.f, 0.f};

    for (int t = blockIdx.x; t < NGROUPS / 4; t += 64) {
        const int ibase = t * 64;
        bf16x8 b0[4], b1[4];
        #pragma unroll
        for (int s = 0; s < 4; ++s) {
            const int gi = ibase + s * 16 + n16;
            const float* isrc = item_emb + (size_t)gi * DIM_C + quad * 8;
            b0[s] = cvt8(isrc);
            b1[s] = cvt8(isrc + 32);
        }
        f32x4 acc[4];
        #pragma unroll
        for (int s = 0; s < 4; ++s) {
            acc[s] = (f32x4){0.f, 0.f, 0.f, 0.f};
            acc[s] = __builtin_amdgcn_mfma_f32_16x16x32_bf16(a0, b0[s], acc[s], 0, 0, 0);
            acc[s] = __builtin_amdgcn_mfma_f32_16x16x32_bf16(a1, b1[s], acc[s], 0, 0, 0);
        }
        #pragma unroll
        for (int s = 0; s < 4; ++s)
            #pragma unroll
            for (int reg = 0; reg < 4; ++reg) {
                const int row = rowBase + quad * 4 + reg;
                const float sc = fminf(fmaxf(acc[s][reg], -CLAMP_C), CLAMP_C);
                const float w = 1.0f - mask[(size_t)row * ITEM_COUNT_C + ibase + s * 16 + n16];
                accExp[reg] += __expf(sc) * w;
            }
    }
    #pragma unroll
    for (int off = 1; off < 16; off <<= 1)
        #pragma unroll
        for (int reg = 0; reg < 4; ++reg)
            accExp[reg] += __shfl_xor(accExp[reg], off, 64);
    if (n16 == 0)
        #pragma unroll
        for (int reg = 0; reg < 4; ++reg)
            atomicAdd(&exp_sum[rowBase + quad * 4 + reg], accExp[reg]);
}

// per-row: 60 sampled scores (exact fp32) + loss math -> row_loss[b]
__global__ void finalize_kernel(
    const float* __restrict__ user_emb,
    const float* __restrict__ item_emb,
    const int*   __restrict__ batch_user,
    const int*   __restrict__ pos_items,
    const int*   __restrict__ top_items,
    const float* __restrict__ exp_sum,
    const int*   __restrict__ is_final,
    float*       __restrict__ row_loss)
{
    __shared__ float ush[DIM_C];
    __shared__ float s_sh[NPOS_C + NTOP_C];
    const int b = blockIdx.x;
    const int tid = threadIdx.x;  // 64 threads
    const int uidx = batch_user[b];
    if (tid < 16)
        *(float4*)&ush[tid * 4] = *(const float4*)(user_emb + (size_t)uidx * DIM_C + tid * 4);
    __syncthreads();

    if (tid < NPOS_C + NTOP_C) {
        const int idx = (tid < NPOS_C) ? pos_items[b * NPOS_C + tid]
                                       : top_items[b * NTOP_C + (tid - NPOS_C)];
        const float* iv = item_emb + (size_t)idx * DIM_C;
        float s = 0.f;
        #pragma unroll
        for (int d4 = 0; d4 < 16; ++d4) {
            const float4 a = *(const float4*)(iv + d4 * 4);
            s += a.x * ush[d4 * 4 + 0] + a.y * ush[d4 * 4 + 1]
               + a.z * ush[d4 * 4 + 2] + a.w * ush[d4 * 4 + 3];
        }
        s_sh[tid] = fminf(fmaxf(s, -CLAMP_C), CLAMP_C);
    }
    __syncthreads();

    if (tid == 0) {
        const float E = exp_sum[b];
        float L;
        if (is_final[0] != 0) {
            float sumExpTop = 0.f, above_top = 0.f;
            for (int i = 0; i < NTOP_C / 2; ++i) {
                const float v = s_sh[NPOS_C + i];
                sumExpTop += __expf(v); above_top += v;
            }
            const float below2 = E - sumExpTop;
            float above_pos = 0.f;
            for (int i = 0; i < NPOS_C; ++i) above_pos += s_sh[i];
            float c = 0.f, below_pos = 0.f;
            for (int i = 0; i < NPOS_C; ++i) {
                c += __expf(s_sh[NPOS_C - 1 - i]);
                below_pos += __logf(fmaxf(c + below2, EPS_C));
            }
            float c2 = 0.f, below_top = 0.f;
            for (int i = 0; i < NTOP_C / 2; ++i) {
                c2 += __expf(s_sh[NPOS_C + NTOP_C / 2 - 1 - i]);
                below_top += __logf(fmaxf(c2 + below2, EPS_C));
            }
            const float pos_KD = below_pos - above_pos;
            float sumExpSub = 0.f, above_sub = 0.f;
            for (int i = 0; i < NTOP_C / 10; ++i) {
                const float v = s_sh[NPOS_C + i];
                sumExpSub += __expf(v); above_sub += v;
            }
            const float below2s = E - sumExpSub;
            float c3 = 0.f, below_sub = 0.f;
            for (int i = 0; i < NTOP_C / 10; ++i) {
                c3 += __expf(s_sh[NPOS_C + NTOP_C / 10 - 1 - i]);
                below_sub += __logf(fmaxf(c3 + below2s, EPS_C));
            }
            const float top_KD = (below_top - above_top) + (below_sub - above_sub);
            L = pos_KD + 0.5f * top_KD;
        } else {
            float sumExpTop = 0.f;
            for (int i = 0; i < NTOP_C; ++i) sumExpTop += __expf(s_sh[NPOS_C + i]);
            const float els = E - sumExpTop;
            L = 0.f;
            for (int j = 0; j < NPOS_C + NTOP_C; ++j) {
                const float a = s_sh[j];
                L += __logf(fmaxf(els + __expf(a), EPS_C)) - a;
            }
        }
        row_loss[b] = L;
    }
}

__global__ void reduce_kernel(const float* __restrict__ rl, float* __restrict__ out) {
    __shared__ float part[16];
    const int tid = threadIdx.x;  // 1024 threads = 16 waves
    float v = rl[tid];
    #pragma unroll
    for (int off = 32; off > 0; off >>= 1) v += __shfl_down(v, off, 64);
    if ((tid & 63) == 0) part[tid >> 6] = v;
    __syncthreads();
    if (tid == 0) {
        float s = 0.f;
        #pragma unroll
        for (int i = 0; i < 16; ++i) s += part[i];
        out[0] = s;
    }
}

extern "C" void kernel_launch(void* const* d_in, const int* in_sizes, int n_in,
                              void* d_out, int out_size, void* d_ws, size_t ws_size,
                              hipStream_t stream) {
    const float* user_emb   = (const float*)d_in[0];
    const float* item_emb   = (const float*)d_in[1];
    const int*   batch_user = (const int*)d_in[2];
    const int*   pos_items  = (const int*)d_in[3];
    const int*   top_items  = (const int*)d_in[4];
    const float* mask       = (const float*)d_in[5];
    const int*   is_final   = (const int*)d_in[6];
    float* out = (float*)d_out;

    float* exp_sum  = (float*)d_ws;       // [B_C]
    float* row_loss = exp_sum + B_C;      // [B_C]
    short* item_bf16 = (short*)(row_loss + B_C);
    const size_t need = 2 * B_C * sizeof(float)
                      + (size_t)NGROUPS * 1024 * sizeof(short);

    hipLaunchKernelGGL(zero_ws_kernel, dim3(1), dim3(B_C), 0, stream, exp_sum);
    if (ws_size >= need) {
        hipLaunchKernelGGL(prep_items_kernel, dim3(NGROUPS * 128 / 256), dim3(256),
                           0, stream, item_emb, item_bf16);
        hipLaunchKernelGGL(expsum_mfma5_kernel, dim3(GX, GY), dim3(256),
                           0, stream, user_emb, item_bf16, batch_user, mask, exp_sum);
    } else {
        hipLaunchKernelGGL(expsum_fallback_kernel, dim3(64, B_C / 64), dim3(256),
                           0, stream, user_emb, item_emb, batch_user, mask, exp_sum);
    }
    hipLaunchKernelGGL(finalize_kernel, dim3(B_C), dim3(64), 0, stream,
                       user_emb, item_emb, batch_user, pos_items, top_items,
                       exp_sum, is_final, row_loss);
    hipLaunchKernelGGL(reduce_kernel, dim3(1), dim3(B_C), 0, stream, row_loss, out);
}

// Round 7
// 589.542 us; speedup vs baseline: 1.0732x; 1.0062x over previous
//
#include <hip/hip_runtime.h>
#include <cstddef>
#include <cstdint>

#define USER_COUNT_C 100000
#define ITEM_COUNT_C 100000
#define DIM_C 64
#define B_C 1024
#define NPOS_C 10
#define NTOP_C 50
#define CLAMP_C 40.0f
#define EPS_C 1e-5f

#define NGROUPS 6250          // 100000/16 item groups (exact)
#define T_TILES 782           // ceil(100000/128) 128-item tiles (last has 32)
#define GX 48                 // tile-range blocks
#define GY 16                 // user blocks (64 users each); 768 blocks = 3/CU
#define MROW 132              // LDS row stride in floats (128 + 4 pad)

using bf16x8 = __attribute__((ext_vector_type(8))) short;
using f32x4  = __attribute__((ext_vector_type(4))) float;

__global__ void zero_ws_kernel(float* __restrict__ ws) {
    ws[threadIdx.x] = 0.0f;  // B_C threads
}

// RNE fp32 -> bf16 bits
__device__ inline short f2bf(float x) {
    uint32_t b = __float_as_uint(x);
    uint32_t r = (b + 0x7fffu + ((b >> 16) & 1u)) >> 16;
    return (short)r;
}

__device__ inline bf16x8 cvt8(const float* __restrict__ p) {
    float4 v0 = *(const float4*)p;
    float4 v1 = *(const float4*)(p + 4);
    bf16x8 r;
    r[0] = f2bf(v0.x); r[1] = f2bf(v0.y); r[2] = f2bf(v0.z); r[3] = f2bf(v0.w);
    r[4] = f2bf(v1.x); r[5] = f2bf(v1.y); r[6] = f2bf(v1.z); r[7] = f2bf(v1.w);
    return r;
}

// item_bf16 frag-ready layout: group g (16 items), half h (k 0/1), quad q,
// item idx16: 8 bf16 at (g*1024 + h*512 + q*128 + idx16*8). Wave frag = 1KB.
__global__ __launch_bounds__(256) void prep_items_kernel(
    const float* __restrict__ item_emb, short* __restrict__ item_bf16) {
    const int t = blockIdx.x * 256 + threadIdx.x;   // NGROUPS*128 total (exact)
    const int n16 = t & 15;
    const int q   = (t >> 4) & 3;
    const int h   = (t >> 6) & 1;
    const int g   = t >> 7;
    const int i   = g * 16 + n16;                   // always < ITEM_COUNT_C
    bf16x8 v = cvt8(item_emb + (size_t)i * DIM_C + h * 32 + q * 8);
    *(bf16x8*)(item_bf16 + (size_t)g * 1024 + h * 512 + q * 128 + n16 * 8) = v;
}

// exp_sum[b] = sum_i exp(clip(u_b . item_i, +-40)) * (1 - mask[b][i])
// ITEMS in A, USERS in B. Mask tile (64 users x 128 items) staged to LDS with
// copy-pattern loads (2 rows x 512B contiguous per instr), consumed in MFMA
// layout via ds_read_b128 (row pad +4 -> <=2-way banks). Each wave computes a
// 32-item quarter of the tile for all 64 users (4 resident B-frag pairs).
__global__ __launch_bounds__(256, 3) void expsum_mfma6_kernel(
    const float* __restrict__ user_emb,
    const short* __restrict__ item_bf16,
    const int*   __restrict__ batch_user,
    const float* __restrict__ mask,
    float*       __restrict__ exp_sum)
{
    __shared__ float mtile[64 * MROW];   // 33.8 KB

    const int tid  = threadIdx.x;
    const int wave = tid >> 6;
    const int lane = tid & 63;
    const int n16  = lane & 15;   // user-in-group / item-in-group index
    const int quad = lane >> 4;   // k-group; C row-group (items)
    const int uBase = blockIdx.y * 64;

    // B fragments: 4 user groups (j*16+n16), resident all kernel
    bf16x8 b0[4], b1[4];
    #pragma unroll
    for (int j = 0; j < 4; ++j) {
        const int uidx = batch_user[uBase + j * 16 + n16];
        const float* us = user_emb + (size_t)uidx * DIM_C + quad * 8;
        b0[j] = cvt8(us);
        b1[j] = cvt8(us + 32);
    }

    // staging constants: idx = k*256+tid -> row=idx>>5, col4=idx&31
    const int srow = tid >> 5;          // rows advance by 8 per k
    const int scol = (tid & 31) * 4;    // float offset within the 128-item tile
    const float* smask = mask + (size_t)(uBase + srow) * ITEM_COUNT_C + scol;
    float* sdst = &mtile[srow * MROW + scol];

    float accE[4] = {0.f, 0.f, 0.f, 0.f};

    for (int tile = blockIdx.x; tile < T_TILES; tile += GX) {
        const int C = tile * 128;

        // ---- stage mask tile: 8 rounds, per instr 2 rows x 512B contiguous
        #pragma unroll
        for (int k = 0; k < 8; ++k) {
            const int gitem = C + scol;           // same col block every round
            float4 v;
            if (gitem < ITEM_COUNT_C)
                v = *(const float4*)(smask + (size_t)(k * 8) * ITEM_COUNT_C + C);
            else
                v = make_float4(1.f, 1.f, 1.f, 1.f);   // OOB -> weight 0
            *(float4*)(sdst + k * 8 * MROW) = v;
        }
        __syncthreads();

        // ---- item fragments for this wave's 32-item quarter
        const short* fp = item_bf16 + (size_t)(tile * 8 + wave * 2) * 1024
                        + quad * 128 + n16 * 8;
        const bf16x8 a00 = *(const bf16x8*)fp;            // items +0..15, k lo
        const bf16x8 a01 = *(const bf16x8*)(fp + 512);    // k hi
        const bf16x8 a10 = *(const bf16x8*)(fp + 1024);   // items +16..31
        const bf16x8 a11 = *(const bf16x8*)(fp + 1536);

        // ---- MFMA: 32 items x 64 users, K=64
        f32x4 acc[2][4];
        #pragma unroll
        for (int j = 0; j < 4; ++j) {
            acc[0][j] = (f32x4){0.f, 0.f, 0.f, 0.f};
            acc[0][j] = __builtin_amdgcn_mfma_f32_16x16x32_bf16(a00, b0[j], acc[0][j], 0, 0, 0);
            acc[0][j] = __builtin_amdgcn_mfma_f32_16x16x32_bf16(a01, b1[j], acc[0][j], 0, 0, 0);
            acc[1][j] = (f32x4){0.f, 0.f, 0.f, 0.f};
            acc[1][j] = __builtin_amdgcn_mfma_f32_16x16x32_bf16(a10, b0[j], acc[1][j], 0, 0, 0);
            acc[1][j] = __builtin_amdgcn_mfma_f32_16x16x32_bf16(a11, b1[j], acc[1][j], 0, 0, 0);
        }

        // ---- epilogue: masks from LDS, clamp -> exp -> weight -> accumulate
        #pragma unroll
        for (int j = 0; j < 4; ++j) {
            #pragma unroll
            for (int ig = 0; ig < 2; ++ig) {
                const int l = wave * 32 + ig * 16 + quad * 4;
                const float4 mv = *(const float4*)&mtile[(j * 16 + n16) * MROW + l];
                const float* mp = (const float*)&mv;
                #pragma unroll
                for (int r = 0; r < 4; ++r) {
                    const float sc = fminf(fmaxf(acc[ig][j][r], -CLAMP_C), CLAMP_C);
                    accE[j] += __expf(sc) * (1.0f - mp[r]);
                }
            }
        }
        __syncthreads();   // protect mtile before next stage
    }

    // reduce over quads (lane bits 4,5): each user's partial lives in 4 lanes
    #pragma unroll
    for (int j = 0; j < 4; ++j) {
        accE[j] += __shfl_xor(accE[j], 16, 64);
        accE[j] += __shfl_xor(accE[j], 32, 64);
    }
    if (quad == 0) {
        #pragma unroll
        for (int j = 0; j < 4; ++j)
            atomicAdd(&exp_sum[uBase + j * 16 + n16], accE[j]);
    }
}

// Fallback (ws too small for bf16 item buffer): fp32 items from global
__global__ __launch_bounds__(256) void expsum_fallback_kernel(
    const float* __restrict__ user_emb,
    const float* __restrict__ item_emb,
    const int*   __restrict__ batch_user,
    const float* __restrict__ mask,
    float*       __restrict__ exp_sum)
{
    const int tid  = threadIdx.x;
    const int wave = tid >> 6;
    const int lane = tid & 63;
    const int n16  = lane & 15;
    const int quad = lane >> 4;
    const int rowBase = blockIdx.y * 64 + wave * 16;

    const int uidx = batch_user[rowBase + n16];
    const float* usrc = user_emb + (size_t)uidx * DIM_C + quad * 8;
    const bf16x8 a0 = cvt8(usrc);
    const bf16x8 a1 = cvt8(usrc + 32);

    float accExp[4] = {0.f, 0.f, 0.f, 0.f};

    for (int t = blockIdx.x; t < NGROUPS / 4; t += 64) {
        const int ibase = t * 64;
        bf16x8 b0[4], b1[4];
        #pragma unroll
        for (int s = 0; s < 4; ++s) {
            const int gi = ibase + s * 16 + n16;
            const float* isrc = item_emb + (size_t)gi * DIM_C + quad * 8;
            b0[s] = cvt8(isrc);
            b1[s] = cvt8(isrc + 32);
        }
        f32x4 acc[4];
        #pragma unroll
        for (int s = 0; s < 4; ++s) {
            acc[s] = (f32x4){0.f, 0.f, 0.f, 0.f};
            acc[s] = __builtin_amdgcn_mfma_f32_16x16x32_bf16(a0, b0[s], acc[s], 0, 0, 0);
            acc[s] = __builtin_amdgcn_mfma_f32_16x16x32_bf16(a1, b1[s], acc[s], 0, 0, 0);
        }
        #pragma unroll
        for (int s = 0; s < 4; ++s)
            #pragma unroll
            for (int reg = 0; reg < 4; ++reg) {
                const int row = rowBase + quad * 4 + reg;
                const float sc = fminf(fmaxf(acc[s][reg], -CLAMP_C), CLAMP_C);
                const float w = 1.0f - mask[(size_t)row * ITEM_COUNT_C + ibase + s * 16 + n16];
                accExp[reg] += __expf(sc) * w;
            }
    }
    #pragma unroll
    for (int off = 1; off < 16; off <<= 1)
        #pragma unroll
        for (int reg = 0; reg < 4; ++reg)
            accExp[reg] += __shfl_xor(accExp[reg], off, 64);
    if (n16 == 0)
        #pragma unroll
        for (int reg = 0; reg < 4; ++reg)
            atomicAdd(&exp_sum[rowBase + quad * 4 + reg], accExp[reg]);
}

// per-row: 60 sampled scores (exact fp32) + loss math -> row_loss[b]
__global__ void finalize_kernel(
    const float* __restrict__ user_emb,
    const float* __restrict__ item_emb,
    const int*   __restrict__ batch_user,
    const int*   __restrict__ pos_items,
    const int*   __restrict__ top_items,
    const float* __restrict__ exp_sum,
    const int*   __restrict__ is_final,
    float*       __restrict__ row_loss)
{
    __shared__ float ush[DIM_C];
    __shared__ float s_sh[NPOS_C + NTOP_C];
    const int b = blockIdx.x;
    const int tid = threadIdx.x;  // 64 threads
    const int uidx = batch_user[b];
    if (tid < 16)
        *(float4*)&ush[tid * 4] = *(const float4*)(user_emb + (size_t)uidx * DIM_C + tid * 4);
    __syncthreads();

    if (tid < NPOS_C + NTOP_C) {
        const int idx = (tid < NPOS_C) ? pos_items[b * NPOS_C + tid]
                                       : top_items[b * NTOP_C + (tid - NPOS_C)];
        const float* iv = item_emb + (size_t)idx * DIM_C;
        float s = 0.f;
        #pragma unroll
        for (int d4 = 0; d4 < 16; ++d4) {
            const float4 a = *(const float4*)(iv + d4 * 4);
            s += a.x * ush[d4 * 4 + 0] + a.y * ush[d4 * 4 + 1]
               + a.z * ush[d4 * 4 + 2] + a.w * ush[d4 * 4 + 3];
        }
        s_sh[tid] = fminf(fmaxf(s, -CLAMP_C), CLAMP_C);
    }
    __syncthreads();

    if (tid == 0) {
        const float E = exp_sum[b];
        float L;
        if (is_final[0] != 0) {
            float sumExpTop = 0.f, above_top = 0.f;
            for (int i = 0; i < NTOP_C / 2; ++i) {
                const float v = s_sh[NPOS_C + i];
                sumExpTop += __expf(v); above_top += v;
            }
            const float below2 = E - sumExpTop;
            float above_pos = 0.f;
            for (int i = 0; i < NPOS_C; ++i) above_pos += s_sh[i];
            float c = 0.f, below_pos = 0.f;
            for (int i = 0; i < NPOS_C; ++i) {
                c += __expf(s_sh[NPOS_C - 1 - i]);
                below_pos += __logf(fmaxf(c + below2, EPS_C));
            }
            float c2 = 0.f, below_top = 0.f;
            for (int i = 0; i < NTOP_C / 2; ++i) {
                c2 += __expf(s_sh[NPOS_C + NTOP_C / 2 - 1 - i]);
                below_top += __logf(fmaxf(c2 + below2, EPS_C));
            }
            const float pos_KD = below_pos - above_pos;
            float sumExpSub = 0.f, above_sub = 0.f;
            for (int i = 0; i < NTOP_C / 10; ++i) {
                const float v = s_sh[NPOS_C + i];
                sumExpSub += __expf(v); above_sub += v;
            }
            const float below2s = E - sumExpSub;
            float c3 = 0.f, below_sub = 0.f;
            for (int i = 0; i < NTOP_C / 10; ++i) {
                c3 += __expf(s_sh[NPOS_C + NTOP_C / 10 - 1 - i]);
                below_sub += __logf(fmaxf(c3 + below2s, EPS_C));
            }
            const float top_KD = (below_top - above_top) + (below_sub - above_sub);
            L = pos_KD + 0.5f * top_KD;
        } else {
            float sumExpTop = 0.f;
            for (int i = 0; i < NTOP_C; ++i) sumExpTop += __expf(s_sh[NPOS_C + i]);
            const float els = E - sumExpTop;
            L = 0.f;
            for (int j = 0; j < NPOS_C + NTOP_C; ++j) {
                const float a = s_sh[j];
                L += __logf(fmaxf(els + __expf(a), EPS_C)) - a;
            }
        }
        row_loss[b] = L;
    }
}

__global__ void reduce_kernel(const float* __restrict__ rl, float* __restrict__ out) {
    __shared__ float part[16];
    const int tid = threadIdx.x;  // 1024 threads = 16 waves
    float v = rl[tid];
    #pragma unroll
    for (int off = 32; off > 0; off >>= 1) v += __shfl_down(v, off, 64);
    if ((tid & 63) == 0) part[tid >> 6] = v;
    __syncthreads();
    if (tid == 0) {
        float s = 0.f;
        #pragma unroll
        for (int i = 0; i < 16; ++i) s += part[i];
        out[0] = s;
    }
}

extern "C" void kernel_launch(void* const* d_in, const int* in_sizes, int n_in,
                              void* d_out, int out_size, void* d_ws, size_t ws_size,
                              hipStream_t stream) {
    const float* user_emb   = (const float*)d_in[0];
    const float* item_emb   = (const float*)d_in[1];
    const int*   batch_user = (const int*)d_in[2];
    const int*   pos_items  = (const int*)d_in[3];
    const int*   top_items  = (const int*)d_in[4];
    const float* mask       = (const float*)d_in[5];
    const int*   is_final   = (const int*)d_in[6];
    float* out = (float*)d_out;

    float* exp_sum  = (float*)d_ws;       // [B_C]
    float* row_loss = exp_sum + B_C;      // [B_C]
    short* item_bf16 = (short*)(row_loss + B_C);
    // frag buffer + slack for tail-tile OOB frag reads (garbage ok, must be in ws)
    const size_t need = 2 * B_C * sizeof(float)
                      + ((size_t)NGROUPS + 16) * 1024 * sizeof(short);

    hipLaunchKernelGGL(zero_ws_kernel, dim3(1), dim3(B_C), 0, stream, exp_sum);
    if (ws_size >= need) {
        hipLaunchKernelGGL(prep_items_kernel, dim3(NGROUPS * 128 / 256), dim3(256),
                           0, stream, item_emb, item_bf16);
        hipLaunchKernelGGL(expsum_mfma6_kernel, dim3(GX, GY), dim3(256),
                           0, stream, user_emb, item_bf16, batch_user, mask, exp_sum);
    } else {
        hipLaunchKernelGGL(expsum_fallback_kernel, dim3(64, B_C / 64), dim3(256),
                           0, stream, user_emb, item_emb, batch_user, mask, exp_sum);
    }
    hipLaunchKernelGGL(finalize_kernel, dim3(B_C), dim3(64), 0, stream,
                       user_emb, item_emb, batch_user, pos_items, top_items,
                       exp_sum, is_final, row_loss);
    hipLaunchKernelGGL(reduce_kernel, dim3(1), dim3(B_C), 0, stream, row_loss, out);
}